// Round 8
// baseline (22054.198 us; speedup 1.0000x reference)
//
#include <hip/hip_runtime.h>

typedef unsigned short u16;
typedef unsigned int   u32;
typedef unsigned long long u64;

#define LTC_B 32
#define LTC_L 1024
#define LTC_D 512
#define LTC_H 512
#define NG 8               // groups
#define NP 16              // producer WGs per group (each owns 32+32 W rows)
#define NBG 4              // batches per group = pipeline chains per group

typedef _Float16 f16x8  __attribute__((ext_vector_type(8)));
typedef _Float16 f16x2t __attribute__((ext_vector_type(2)));
typedef float    f32x4  __attribute__((ext_vector_type(4)));

static __device__ __forceinline__ u32 packh(float a, float b) {
    f16x2t p; p[0] = (_Float16)a; p[1] = (_Float16)b;
    return __builtin_bit_cast(u32, p);
}
static __device__ __forceinline__ float unplo(u32 w) {
    return (float)__builtin_bit_cast(f16x2t, w)[0];
}
static __device__ __forceinline__ float unphi(u32 w) {
    return (float)__builtin_bit_cast(f16x2t, w)[1];
}
static __device__ __forceinline__ float sigm(float x) {
    return 1.f / (1.f + __expf(-x));
}
static __device__ __forceinline__ float tanh_f(float x) {
    float e = __expf(2.f * x);          // inf-safe: e=inf -> 1, e=0 -> -1
    return 1.f - 2.f / (e + 1.f);
}
static __device__ __forceinline__ f16x8 cvt8(const float* p) {
    const float4 a = *(const float4*)p;
    const float4 b = *(const float4*)(p + 4);
    f16x8 r;
    r[0] = (_Float16)a.x; r[1] = (_Float16)a.y; r[2] = (_Float16)a.z; r[3] = (_Float16)a.w;
    r[4] = (_Float16)b.x; r[5] = (_Float16)b.y; r[6] = (_Float16)b.z; r[7] = (_Float16)b.w;
    return r;
}

// ---------------------------------------------------------------------------
// C[M,512](f16) = A[M,512](f32) . W[:,:512]^T(f32, row stride ldb) + bias(f32)
// ---------------------------------------------------------------------------
__global__ __launch_bounds__(256) void gemm_a32_c16(
    const float* __restrict__ A, const float* __restrict__ W, int ldb,
    const float* __restrict__ bias, u16* __restrict__ C)
{
    const int wave = threadIdx.x >> 6;
    const int lane = threadIdx.x & 63;
    const int tile = blockIdx.x * 4 + wave;
    const int nt = tile & 7;
    const int mt = tile >> 3;
    const int r16 = lane & 15;
    const int kq  = (lane >> 4) * 8;

    const float* ap = A + (size_t)(mt * 64 + r16) * LTC_D + kq;
    const float* wp = W + (size_t)(nt * 64 + r16) * ldb + kq;

    f32x4 acc[4][4];
    #pragma unroll
    for (int i = 0; i < 4; ++i)
        #pragma unroll
        for (int jj = 0; jj < 4; ++jj) acc[i][jj] = (f32x4){0.f, 0.f, 0.f, 0.f};

    for (int ks = 0; ks < 16; ++ks) {
        f16x8 af[4], bf[4];
        #pragma unroll
        for (int t = 0; t < 4; ++t) {
            af[t] = cvt8(ap + (size_t)t * 16 * LTC_D + ks * 32);
            bf[t] = cvt8(wp + (size_t)t * 16 * ldb  + ks * 32);
        }
        #pragma unroll
        for (int mi = 0; mi < 4; ++mi)
            #pragma unroll
            for (int ni = 0; ni < 4; ++ni)
                acc[mi][ni] = __builtin_amdgcn_mfma_f32_16x16x32_f16(
                    af[mi], bf[ni], acc[mi][ni], 0, 0, 0);
    }
    const int row = (lane >> 4) * 4;   // C/D: col=lane&15 (n), row=(lane>>4)*4+reg (m)
    const int col = lane & 15;
    #pragma unroll
    for (int ni = 0; ni < 4; ++ni) {
        const int n = nt * 64 + ni * 16 + col;
        const float bv = bias[n];
        #pragma unroll
        for (int mi = 0; mi < 4; ++mi)
            #pragma unroll
            for (int r = 0; r < 4; ++r) {
                _Float16 h = (_Float16)(acc[mi][ni][r] + bv);
                C[(size_t)(mt * 64 + mi * 16 + row + r) * LTC_H + n] =
                    __builtin_bit_cast(u16, h);
            }
    }
}

// ---------------------------------------------------------------------------
// C[M,512](f32) = A[M,512](f16) . W^T(f32, row stride 512) + bias(f32)
// ---------------------------------------------------------------------------
__global__ __launch_bounds__(256) void gemm_a16_c32(
    const u16* __restrict__ A, const float* __restrict__ W,
    const float* __restrict__ bias, float* __restrict__ C)
{
    const int wave = threadIdx.x >> 6;
    const int lane = threadIdx.x & 63;
    const int tile = blockIdx.x * 4 + wave;
    const int nt = tile & 7;
    const int mt = tile >> 3;
    const int r16 = lane & 15;
    const int kq  = (lane >> 4) * 8;

    const _Float16* ap = (const _Float16*)A + (size_t)(mt * 64 + r16) * LTC_D + kq;
    const float*    wp = W + (size_t)(nt * 64 + r16) * LTC_H + kq;

    f32x4 acc[4][4];
    #pragma unroll
    for (int i = 0; i < 4; ++i)
        #pragma unroll
        for (int jj = 0; jj < 4; ++jj) acc[i][jj] = (f32x4){0.f, 0.f, 0.f, 0.f};

    for (int ks = 0; ks < 16; ++ks) {
        f16x8 af[4], bf[4];
        #pragma unroll
        for (int t = 0; t < 4; ++t) {
            af[t] = *(const f16x8*)(ap + (size_t)t * 16 * LTC_D + ks * 32);
            bf[t] = cvt8(wp + (size_t)t * 16 * LTC_H + ks * 32);
        }
        #pragma unroll
        for (int mi = 0; mi < 4; ++mi)
            #pragma unroll
            for (int ni = 0; ni < 4; ++ni)
                acc[mi][ni] = __builtin_amdgcn_mfma_f32_16x16x32_f16(
                    af[mi], bf[ni], acc[mi][ni], 0, 0, 0);
    }
    const int row = (lane >> 4) * 4;
    const int col = lane & 15;
    #pragma unroll
    for (int ni = 0; ni < 4; ++ni) {
        const int n = nt * 64 + ni * 16 + col;
        const float bv = bias[n];
        #pragma unroll
        for (int mi = 0; mi < 4; ++mi)
            #pragma unroll
            for (int r = 0; r < 4; ++r)
                C[(size_t)(mt * 64 + mi * 16 + row + r) * LTC_H + n] =
                    acc[mi][ni][r] + bv;
    }
}

// ---------------------------------------------------------------------------
// ODE scan: 8 groups x 4 batches, 16 producer WGs per group (128 WGs).
// Exchange = round-7's validated LLC channel (stamped u64, relaxed agent
// atomics, parity double-buffer, bounded spins). NEW: the 4 batches of a
// group are 4 INDEPENDENT pipeline chains. Each sub-step runs 4 chain-slots:
//   slot c: poll chain c gen k-1 (published ~1 sub-step ago -> RTT already
//           elapsed) | barrier | matvec_c | barrier | update+publish gen k.
// The serialized LLC round-trip that dominated round 7 (one per sub-step on
// a single chain) is overlapped by the other 3 chains' compute. Polls are
// 1 word/thread/slot (thread tid's words all belong to producer tid>>4),
// cutting failing-sweep LLC traffic 4x. All hTu accesses barrier-ordered;
// per-chain skew bound & parity-overwrite induction unchanged from round 7.
// ---------------------------------------------------------------------------
__global__ __launch_bounds__(256) void ltc_scan(
    u32* __restrict__ drive,            // f16 pairs; rewritten with fwd
    const u32* __restrict__ gatex,      // f16 pairs
    const float* __restrict__ W_rec,
    const float* __restrict__ W_gate,
    const float* __restrict__ log_tau,
    u64* __restrict__ hbuf,             // [2 par][8 g][4 chain][256] stamped
    float* __restrict__ hlast)
{
    const int g   = blockIdx.x & 7;     // group
    const int p   = blockIdx.x >> 3;    // producer slice 0..15
    const int tid = threadIdx.x;
    const int lane = tid & 63;
    const int wv   = tid >> 6;          // n-tile: 0-1 rec rows, 2-3 gate rows

    __shared__ u32 hTu[16][260];        // h f16 pairs; row c = chain c (c<4)
    __shared__ float redc[4][68];       // per-chain matvec result [n]

    // ---- one-time: B-fragments (my 32 W_rec + 32 Wg_h rows) into registers
    const int nl = wv * 16 + (lane & 15);      // 0..63
    const int kq = (lane >> 4) * 8;
    const float* wrow = (nl < 32)
        ? (W_rec  + (size_t)(32 * p + nl) * LTC_H)
        : (W_gate + (size_t)(32 * p + nl - 32) * (LTC_D + LTC_H) + LTC_D);
    f16x8 Wf[16];
    #pragma unroll
    for (int ks = 0; ks < 16; ++ks) Wf[ks] = cvt8(wrow + ks * 32 + kq);

    for (int i = tid; i < 16 * 260; i += 256) (&hTu[0][0])[i] = 0;  // h0 = 0
    __syncthreads();

    // ---- update-thread setup (tid<64: batch/chain ub = tid>>4, pair jp)
    const int ub = tid >> 4;
    const int jp = tid & 15;
    const int j0 = 32 * p + 2 * jp;
    const int gb = g * NBG + ub;        // global batch
    float h0 = 0.f, h1 = 0.f, stau0 = 0.f, stau1 = 0.f;
    size_t dwofs = 0;
    if (tid < 64) {
        stau0 = (1.f / 6.f) * __expf(-log_tau[j0]);
        stau1 = (1.f / 6.f) * __expf(-log_tau[j0 + 1]);
        dwofs = (size_t)gb * LTC_L * 256 + 16 * p + jp;
    }

    const _Float16* hrow = (const _Float16*)&hTu[lane & 15][0];
    u32 kp1 = 0;
    int budget = 1 << 22;               // global failing-poll budget (no hangs)

    // prime l=0 inputs
    u32 dw = 0, gw = 0;
    if (tid < 64) { dw = drive[dwofs]; gw = gatex[dwofs]; }

    for (int l = 0; l < LTC_L; ++l) {
        const float d0 = unplo(dw), d1 = unphi(dw);
        const float gx0 = unplo(gw), gx1 = unphi(gw);
        u32 dn = 0, gn = 0;
        if (tid < 64 && l + 1 < LTC_L) {
            dn = drive[dwofs + (size_t)(l + 1) * 256];
            gn = gatex[dwofs + (size_t)(l + 1) * 256];
        }
        #pragma unroll 1
        for (int s = 0; s < 6; ++s) {
            ++kp1;
            const u32 pk = kp1 - 1;     // generation being gathered
            const size_t pubbase = (size_t)(((kp1 & 1u) * NG + g) * NBG) * 256;
            const size_t polbase = (size_t)(((pk  & 1u) * NG + g) * NBG) * 256;
            #pragma unroll
            for (int c = 0; c < NBG; ++c) {
                // ---- poll chain c gen k-1 (1 word/thread; RTT mostly elapsed)
                if (pk) {
                    const u64* sb = hbuf + polbase + (size_t)c * 256 + tid;
                    u64 v;
                    do {
                        v = __hip_atomic_load(sb, __ATOMIC_RELAXED,
                                              __HIP_MEMORY_SCOPE_AGENT);
                    } while ((u32)(v >> 32) != pk && --budget > 0);
                    hTu[c][tid] = (u32)v;
                }
                __syncthreads();
                // ---- matvec chain c: acc[m] over 16 K-chunks (M row c used)
                f32x4 acc0 = (f32x4){0.f, 0.f, 0.f, 0.f}, acc1 = acc0;
                #pragma unroll
                for (int ks = 0; ks < 16; ks += 2) {
                    const f16x8 a0 = *(const f16x8*)(hrow + ks * 32 + kq);
                    const f16x8 a1 = *(const f16x8*)(hrow + (ks + 1) * 32 + kq);
                    acc0 = __builtin_amdgcn_mfma_f32_16x16x32_f16(a0, Wf[ks],     acc0, 0, 0, 0);
                    acc1 = __builtin_amdgcn_mfma_f32_16x16x32_f16(a1, Wf[ks + 1], acc1, 0, 0, 0);
                }
                // batch c lives in M rows 0..3 -> register quad 0, reg index c
                if (lane < 16) redc[c][wv * 16 + lane] = acc0[c] + acc1[c];
                __syncthreads();
                // ---- update + publish chain c (threads 16c..16c+15)
                if (tid < 64 && ub == c) {
                    const float rec0 = redc[c][2 * jp],      gh0 = redc[c][32 + 2 * jp];
                    const float rec1 = redc[c][2 * jp + 1],  gh1 = redc[c][33 + 2 * jp];
                    h0 += stau0 * (sigm(gx0 + gh0) * tanh_f(d0 + rec0) - h0);
                    h1 += stau1 * (sigm(gx1 + gh1) * tanh_f(d1 + rec1) - h1);
                    const u64 v = ((u64)kp1 << 32) | (u64)packh(h0, h1);
                    __hip_atomic_store(hbuf + pubbase + (size_t)c * 256 + 16 * p + jp,
                                       v, __ATOMIC_RELAXED, __HIP_MEMORY_SCOPE_AGENT);
                }
            }
        }
        if (tid < 64) drive[dwofs + (size_t)l * 256] = packh(h0, h1);  // fwd
        dw = dn; gw = gn;
    }
    if (tid < 64) {
        hlast[(size_t)gb * LTC_H + j0]     = h0;
        hlast[(size_t)gb * LTC_H + j0 + 1] = h1;
    }
}

// ---------------------------------------------------------------------------
extern "C" void kernel_launch(void* const* d_in, const int* in_sizes, int n_in,
                              void* d_out, int out_size, void* d_ws, size_t ws_size,
                              hipStream_t stream)
{
    const float* x       = (const float*)d_in[0];
    const float* log_tau = (const float*)d_in[1];
    const float* W_in    = (const float*)d_in[2];
    const float* b_in    = (const float*)d_in[3];
    const float* W_rec   = (const float*)d_in[4];
    const float* W_gate  = (const float*)d_in[5];
    const float* b_gate  = (const float*)d_in[6];
    const float* W_out   = (const float*)d_in[7];
    const float* b_out   = (const float*)d_in[8];

    float* out   = (float*)d_out;                       // (32,1024,512) fp32
    float* hlast = out + (size_t)LTC_B * LTC_L * LTC_H; // (32,512) fp32

    u32* ws    = (u32*)d_ws;                   // 64 MB + 128 KB used
    u32* drive = ws;                           // 8388608 u32 (f16 pairs)
    u32* gatex = ws + 8388608;                 // 8388608 u32
    u64* hbuf  = (u64*)(ws + 16777216);        // 16384 u64 stamped pairs

    const int blocks = (LTC_B * LTC_L / 64) * (LTC_H / 64) / 4;   // 1024

    gemm_a32_c16<<<blocks, 256, 0, stream>>>(x, W_in, LTC_D, b_in, (u16*)drive);
    gemm_a32_c16<<<blocks, 256, 0, stream>>>(x, W_gate, LTC_D + LTC_H, b_gate, (u16*)gatex);
    ltc_scan<<<NG * NP, 256, 0, stream>>>(drive, gatex, W_rec, W_gate, log_tau,
                                          hbuf, hlast);
    gemm_a16_c32<<<blocks, 256, 0, stream>>>((const u16*)drive, W_out, b_out, out);
}

// Round 9
// 17001.187 us; speedup vs baseline: 1.2972x; 1.2972x over previous
//
#include <hip/hip_runtime.h>

typedef unsigned short u16;
typedef unsigned int   u32;
typedef unsigned long long u64;

#define LTC_B 32
#define LTC_L 1024
#define LTC_D 512
#define LTC_H 512
#define NG 8               // groups
#define NP 16              // producer WGs per group (each owns 32+32 W rows)
#define NBG 4              // batches per group

typedef _Float16 f16x8  __attribute__((ext_vector_type(8)));
typedef _Float16 f16x2t __attribute__((ext_vector_type(2)));
typedef float    f32x4  __attribute__((ext_vector_type(4)));
typedef unsigned int u32x4 __attribute__((ext_vector_type(4)));

static __device__ __forceinline__ u32 packh(float a, float b) {
    f16x2t p; p[0] = (_Float16)a; p[1] = (_Float16)b;
    return __builtin_bit_cast(u32, p);
}
static __device__ __forceinline__ float unplo(u32 w) {
    return (float)__builtin_bit_cast(f16x2t, w)[0];
}
static __device__ __forceinline__ float unphi(u32 w) {
    return (float)__builtin_bit_cast(f16x2t, w)[1];
}
static __device__ __forceinline__ float sigm(float x) {
    return 1.f / (1.f + __expf(-x));
}
static __device__ __forceinline__ float tanh_f(float x) {
    float e = __expf(2.f * x);          // inf-safe: e=inf -> 1, e=0 -> -1
    return 1.f - 2.f / (e + 1.f);
}
static __device__ __forceinline__ f16x8 cvt8(const float* p) {
    const float4 a = *(const float4*)p;
    const float4 b = *(const float4*)(p + 4);
    f16x8 r;
    r[0] = (_Float16)a.x; r[1] = (_Float16)a.y; r[2] = (_Float16)a.z; r[3] = (_Float16)a.w;
    r[4] = (_Float16)b.x; r[5] = (_Float16)b.y; r[6] = (_Float16)b.z; r[7] = (_Float16)b.w;
    return r;
}
static __device__ __forceinline__ bool stamp4(u64 a, u64 b, u64 c, u64 d, u32 k) {
    return ((u32)(a >> 32) == k) & ((u32)(b >> 32) == k) &
           ((u32)(c >> 32) == k) & ((u32)(d >> 32) == k);
}
// fast sweep: 32B contiguous via 2 L1-bypass 16B loads (served by the XCD's
// shared L2 when the producer WG is co-resident), single waitcnt.
static __device__ __forceinline__ void ldfast32(const u64* p,
        u64& a0, u64& a1, u64& a2, u64& a3) {
    u32x4 r0, r1;
    asm volatile(
        "global_load_dwordx4 %0, %2, off sc0\n\t"
        "global_load_dwordx4 %1, %3, off sc0\n\t"
        "s_waitcnt vmcnt(0)"
        : "=&v"(r0), "=&v"(r1)
        : "v"(p), "v"(p + 2)
        : "memory");
    a0 = ((u64)r0.y << 32) | r0.x;  a1 = ((u64)r0.w << 32) | r0.z;
    a2 = ((u64)r1.y << 32) | r1.x;  a3 = ((u64)r1.w << 32) | r1.z;
}

// ---------------------------------------------------------------------------
// C[M,512](f16) = A[M,512](f32) . W[:,:512]^T(f32, row stride ldb) + bias(f32)
// ---------------------------------------------------------------------------
__global__ __launch_bounds__(256) void gemm_a32_c16(
    const float* __restrict__ A, const float* __restrict__ W, int ldb,
    const float* __restrict__ bias, u16* __restrict__ C)
{
    const int wave = threadIdx.x >> 6;
    const int lane = threadIdx.x & 63;
    const int tile = blockIdx.x * 4 + wave;
    const int nt = tile & 7;
    const int mt = tile >> 3;
    const int r16 = lane & 15;
    const int kq  = (lane >> 4) * 8;

    const float* ap = A + (size_t)(mt * 64 + r16) * LTC_D + kq;
    const float* wp = W + (size_t)(nt * 64 + r16) * ldb + kq;

    f32x4 acc[4][4];
    #pragma unroll
    for (int i = 0; i < 4; ++i)
        #pragma unroll
        for (int jj = 0; jj < 4; ++jj) acc[i][jj] = (f32x4){0.f, 0.f, 0.f, 0.f};

    for (int ks = 0; ks < 16; ++ks) {
        f16x8 af[4], bf[4];
        #pragma unroll
        for (int t = 0; t < 4; ++t) {
            af[t] = cvt8(ap + (size_t)t * 16 * LTC_D + ks * 32);
            bf[t] = cvt8(wp + (size_t)t * 16 * ldb  + ks * 32);
        }
        #pragma unroll
        for (int mi = 0; mi < 4; ++mi)
            #pragma unroll
            for (int ni = 0; ni < 4; ++ni)
                acc[mi][ni] = __builtin_amdgcn_mfma_f32_16x16x32_f16(
                    af[mi], bf[ni], acc[mi][ni], 0, 0, 0);
    }
    const int row = (lane >> 4) * 4;   // C/D: col=lane&15 (n), row=(lane>>4)*4+reg (m)
    const int col = lane & 15;
    #pragma unroll
    for (int ni = 0; ni < 4; ++ni) {
        const int n = nt * 64 + ni * 16 + col;
        const float bv = bias[n];
        #pragma unroll
        for (int mi = 0; mi < 4; ++mi)
            #pragma unroll
            for (int r = 0; r < 4; ++r) {
                _Float16 h = (_Float16)(acc[mi][ni][r] + bv);
                C[(size_t)(mt * 64 + mi * 16 + row + r) * LTC_H + n] =
                    __builtin_bit_cast(u16, h);
            }
    }
}

// ---------------------------------------------------------------------------
// C[M,512](f32) = A[M,512](f16) . W^T(f32, row stride 512) + bias(f32)
// ---------------------------------------------------------------------------
__global__ __launch_bounds__(256) void gemm_a16_c32(
    const u16* __restrict__ A, const float* __restrict__ W,
    const float* __restrict__ bias, float* __restrict__ C)
{
    const int wave = threadIdx.x >> 6;
    const int lane = threadIdx.x & 63;
    const int tile = blockIdx.x * 4 + wave;
    const int nt = tile & 7;
    const int mt = tile >> 3;
    const int r16 = lane & 15;
    const int kq  = (lane >> 4) * 8;

    const _Float16* ap = (const _Float16*)A + (size_t)(mt * 64 + r16) * LTC_D + kq;
    const float*    wp = W + (size_t)(nt * 64 + r16) * LTC_H + kq;

    f32x4 acc[4][4];
    #pragma unroll
    for (int i = 0; i < 4; ++i)
        #pragma unroll
        for (int jj = 0; jj < 4; ++jj) acc[i][jj] = (f32x4){0.f, 0.f, 0.f, 0.f};

    for (int ks = 0; ks < 16; ++ks) {
        f16x8 af[4], bf[4];
        #pragma unroll
        for (int t = 0; t < 4; ++t) {
            af[t] = *(const f16x8*)(ap + (size_t)t * 16 * LTC_D + ks * 32);
            bf[t] = cvt8(wp + (size_t)t * 16 * LTC_H + ks * 32);
        }
        #pragma unroll
        for (int mi = 0; mi < 4; ++mi)
            #pragma unroll
            for (int ni = 0; ni < 4; ++ni)
                acc[mi][ni] = __builtin_amdgcn_mfma_f32_16x16x32_f16(
                    af[mi], bf[ni], acc[mi][ni], 0, 0, 0);
    }
    const int row = (lane >> 4) * 4;
    const int col = lane & 15;
    #pragma unroll
    for (int ni = 0; ni < 4; ++ni) {
        const int n = nt * 64 + ni * 16 + col;
        const float bv = bias[n];
        #pragma unroll
        for (int mi = 0; mi < 4; ++mi)
            #pragma unroll
            for (int r = 0; r < 4; ++r)
                C[(size_t)(mt * 64 + mi * 16 + row + r) * LTC_H + n] =
                    acc[mi][ni][r] + bv;
    }
}

// ---------------------------------------------------------------------------
// ODE scan: round-7 structure (8 groups x 4 batches, 16 producer WGs/group,
// stamped u64 exchange, parity double-buffer, bounded spins) + adaptive
// intra-XCD fast path:
//  - producers DUAL publish fire-and-forget: plain store (lands in own XCD L2)
//    + sc1 relaxed atomic (LLC, the validated channel).
//  - consumers try <=8 fast sc0 sweeps (shared-L2 hit if co-XCD; stale stamps
//    can never falsely match), else the proven LLC loop. Per-thread trust
//    counter disables a dead fast path (re-armed every 64 substeps: ~30 cyc/
//    substep amortized probe cost). Worst case == round 7; best case r drops
//    from ~3300 to ~700 cyc.
//  - gather layout [word][chain]: each thread's 4 poll words are 32B
//    contiguous (2 packets/sweep instead of 4).
// ---------------------------------------------------------------------------
__global__ __launch_bounds__(256) void ltc_scan(
    u32* __restrict__ drive,            // f16 pairs; rewritten with fwd
    const u32* __restrict__ gatex,      // f16 pairs
    const float* __restrict__ W_rec,
    const float* __restrict__ W_gate,
    const float* __restrict__ log_tau,
    u64* __restrict__ hfast,            // [2 par][8 g][256 word][4 chain]
    u64* __restrict__ hsafe,            // LLC mirror, same layout
    float* __restrict__ hlast)
{
    const int g   = blockIdx.x & 7;     // group
    const int p   = blockIdx.x >> 3;    // producer slice 0..15
    const int tid = threadIdx.x;
    const int lane = tid & 63;
    const int wv   = tid >> 6;          // n-tile: 0-1 rec rows, 2-3 gate rows

    __shared__ u32 hTu[16][260];        // h f16 pairs; rows 0-3 = batches
    __shared__ float red[64][17];       // matvec results [n][m]

    // ---- one-time: B-fragments (my 32 W_rec + 32 Wg_h rows) into registers
    const int nl = wv * 16 + (lane & 15);      // 0..63
    const int kq = (lane >> 4) * 8;
    const float* wrow = (nl < 32)
        ? (W_rec  + (size_t)(32 * p + nl) * LTC_H)
        : (W_gate + (size_t)(32 * p + nl - 32) * (LTC_D + LTC_H) + LTC_D);
    f16x8 Wf[16];
    #pragma unroll
    for (int ks = 0; ks < 16; ++ks) Wf[ks] = cvt8(wrow + ks * 32 + kq);

    for (int i = tid; i < 16 * 260; i += 256) (&hTu[0][0])[i] = 0;  // h0 = 0
    __syncthreads();

    // ---- update-thread setup (tid<64: chain ub = tid>>4, pair jp)
    const int ub = tid >> 4;
    const int jp = tid & 15;
    const int j0 = 32 * p + 2 * jp;
    const int gb = g * NBG + ub;        // global batch
    float h0 = 0.f, h1 = 0.f, stau0 = 0.f, stau1 = 0.f;
    size_t dwofs = 0;
    if (tid < 64) {
        stau0 = (1.f / 6.f) * __expf(-log_tau[j0]);
        stau1 = (1.f / 6.f) * __expf(-log_tau[j0 + 1]);
        dwofs = (size_t)gb * LTC_L * 256 + 16 * p + jp;
    }

    const _Float16* hrow = (const _Float16*)&hTu[lane & 15][0];
    u32 kp1 = 0;
    int budget = 1 << 22;               // global failing-poll budget (no hangs)
    int trust  = 4;                     // fast-path confidence

    // prime l=0 inputs
    u32 dw = 0, gw = 0;
    if (tid < 64) { dw = drive[dwofs]; gw = gatex[dwofs]; }

    for (int l = 0; l < LTC_L; ++l) {
        const float d0 = unplo(dw), d1 = unphi(dw);
        const float gx0 = unplo(gw), gx1 = unphi(gw);
        u32 dn = 0, gn = 0;
        if (tid < 64 && l + 1 < LTC_L) {
            dn = drive[dwofs + (size_t)(l + 1) * 256];
            gn = gatex[dwofs + (size_t)(l + 1) * 256];
        }
        #pragma unroll 1
        for (int s = 0; s < 6; ++s) {
            // ---- matvec: red[n][m] = sum_k h[m,k] * Wrow(n)[k] (2 acc chains)
            f32x4 acc0 = (f32x4){0.f, 0.f, 0.f, 0.f}, acc1 = acc0;
            #pragma unroll
            for (int ks = 0; ks < 16; ks += 2) {
                const f16x8 a0 = *(const f16x8*)(hrow + ks * 32 + kq);
                const f16x8 a1 = *(const f16x8*)(hrow + (ks + 1) * 32 + kq);
                acc0 = __builtin_amdgcn_mfma_f32_16x16x32_f16(a0, Wf[ks],     acc0, 0, 0, 0);
                acc1 = __builtin_amdgcn_mfma_f32_16x16x32_f16(a1, Wf[ks + 1], acc1, 0, 0, 0);
            }
            {
                const int n  = wv * 16 + (lane & 15);
                const int rb = (lane >> 4) * 4;
                #pragma unroll
                for (int r = 0; r < 4; ++r) red[n][rb + r] = acc0[r] + acc1[r];
            }
            __syncthreads();
            ++kp1;
            const size_t pbase = (size_t)(((kp1 & 1u) * NG + g)) * (256 * NBG);
            // ---- update + dual publish (both fire-and-forget, pre-gather) --
            if (tid < 64) {
                const float rec0 = red[2 * jp][ub],     gh0 = red[32 + 2 * jp][ub];
                const float rec1 = red[2 * jp + 1][ub], gh1 = red[32 + 2 * jp + 1][ub];
                h0 += stau0 * (sigm(gx0 + gh0) * tanh_f(d0 + rec0) - h0);
                h1 += stau1 * (sigm(gx1 + gh1) * tanh_f(d1 + rec1) - h1);
                const u64 v = ((u64)kp1 << 32) | (u64)packh(h0, h1);
                const size_t w = pbase + (size_t)(16 * p + jp) * NBG + ub;
                *(volatile u64*)(hfast + w) = v;                  // own XCD L2
                __hip_atomic_store(hsafe + w, v, __ATOMIC_RELAXED,
                                   __HIP_MEMORY_SCOPE_AGENT);     // LLC
            }
            // ---- gather: word tid, chains 0..3 (32B contiguous) ----
            {
                u64 a0 = 0, a1 = 0, a2 = 0, a3 = 0;
                bool hit = false;
                if (trust > 0) {        // bounded fast probe (XCD L2)
                    const u64* fb = hfast + pbase + (size_t)tid * NBG;
                    for (int it = 0; it < 8 && !hit; ++it) {
                        ldfast32(fb, a0, a1, a2, a3);
                        hit = stamp4(a0, a1, a2, a3, kp1);
                    }
                    trust = hit ? 4 : (trust - 1);
                } else if ((kp1 & 63u) == 0u) {
                    trust = 1;          // periodic re-arm probe
                }
                if (!hit) {             // proven LLC path (round 7)
                    const u64* sb = hsafe + pbase + (size_t)tid * NBG;
                    do {
                        a0 = __hip_atomic_load(sb,     __ATOMIC_RELAXED,
                                               __HIP_MEMORY_SCOPE_AGENT);
                        a1 = __hip_atomic_load(sb + 1, __ATOMIC_RELAXED,
                                               __HIP_MEMORY_SCOPE_AGENT);
                        a2 = __hip_atomic_load(sb + 2, __ATOMIC_RELAXED,
                                               __HIP_MEMORY_SCOPE_AGENT);
                        a3 = __hip_atomic_load(sb + 3, __ATOMIC_RELAXED,
                                               __HIP_MEMORY_SCOPE_AGENT);
                        hit = stamp4(a0, a1, a2, a3, kp1);
                    } while (!hit && --budget > 0);
                }
                hTu[0][tid] = (u32)a0; hTu[1][tid] = (u32)a1;
                hTu[2][tid] = (u32)a2; hTu[3][tid] = (u32)a3;
            }
            __syncthreads();
        }
        if (tid < 64) drive[dwofs + (size_t)l * 256] = packh(h0, h1);  // fwd
        dw = dn; gw = gn;
    }
    if (tid < 64) {
        hlast[(size_t)gb * LTC_H + j0]     = h0;
        hlast[(size_t)gb * LTC_H + j0 + 1] = h1;
    }
}

// ---------------------------------------------------------------------------
extern "C" void kernel_launch(void* const* d_in, const int* in_sizes, int n_in,
                              void* d_out, int out_size, void* d_ws, size_t ws_size,
                              hipStream_t stream)
{
    const float* x       = (const float*)d_in[0];
    const float* log_tau = (const float*)d_in[1];
    const float* W_in    = (const float*)d_in[2];
    const float* b_in    = (const float*)d_in[3];
    const float* W_rec   = (const float*)d_in[4];
    const float* W_gate  = (const float*)d_in[5];
    const float* b_gate  = (const float*)d_in[6];
    const float* W_out   = (const float*)d_in[7];
    const float* b_out   = (const float*)d_in[8];

    float* out   = (float*)d_out;                       // (32,1024,512) fp32
    float* hlast = out + (size_t)LTC_B * LTC_L * LTC_H; // (32,512) fp32

    u32* ws    = (u32*)d_ws;                   // 64 MB + 256 KB used
    u32* drive = ws;                           // 8388608 u32 (f16 pairs)
    u32* gatex = ws + 8388608;                 // 8388608 u32
    u64* hfast = (u64*)(ws + 16777216);        // 16384 u64 stamped pairs
    u64* hsafe = hfast + 16384;                // LLC mirror

    const int blocks = (LTC_B * LTC_L / 64) * (LTC_H / 64) / 4;   // 1024

    gemm_a32_c16<<<blocks, 256, 0, stream>>>(x, W_in, LTC_D, b_in, (u16*)drive);
    gemm_a32_c16<<<blocks, 256, 0, stream>>>(x, W_gate, LTC_D + LTC_H, b_gate, (u16*)gatex);
    ltc_scan<<<NG * NP, 256, 0, stream>>>(drive, gatex, W_rec, W_gate, log_tau,
                                          hfast, hsafe, hlast);
    gemm_a16_c32<<<blocks, 256, 0, stream>>>((const u16*)drive, W_out, b_out, out);
}